// Round 11
// baseline (172.967 us; speedup 1.0000x reference)
//
#include <hip/hip_runtime.h>

#define HC 256
#define WC 256
#define CC 96
#define BB 4
#define OH 258
#define OW 258
#define PLANE 65536
#define NQUAD 64                     // 256 r-rows as 64 quads of 4 rows
#define CGW 24                       // channels per wave (4 waves/block)
#define K2_JOBS (BB * 9 * OH)        // 9288 (one wave per out row)
#define K2_BLOCKS ((K2_JOBS + 3) / 4)
#define WS_NEEDED ((size_t)BB * 9 * PLANE * 4)   // 9.44 MB of r

__device__ __forceinline__ float4 ld4(const float* p){ return *reinterpret_cast<const float4*>(p); }
__device__ __forceinline__ void st4(float* p, float4 v){ *reinterpret_cast<float4*>(p) = v; }

// acc[A..C] = ti=-1,0,+1; window w0..w5 = x2 cols 4t-1 .. 4t+4 of one x2 row
__device__ __forceinline__ void tap6(float4& A, float4& B, float4& C, const float4 a,
                                     float w0, float w1, float w2, float w3, float w4, float w5)
{
    A.x = fmaf(a.x, w0, A.x); A.y = fmaf(a.y, w1, A.y); A.z = fmaf(a.z, w2, A.z); A.w = fmaf(a.w, w3, A.w);
    B.x = fmaf(a.x, w1, B.x); B.y = fmaf(a.y, w2, B.y); B.z = fmaf(a.z, w3, B.z); B.w = fmaf(a.w, w4, B.w);
    C.x = fmaf(a.x, w2, C.x); C.y = fmaf(a.y, w3, C.y); C.z = fmaf(a.z, w4, C.z); C.w = fmaf(a.w, w5, C.w);
}

// ---------------- kernel 1: r(h,w,d) = sum_c x1[c,h,w]*x2[c,h+tj-1,w+ti-1] ----------------
// wave = full 256-wide row-QUAD (h0..h0+3) x 24 channels; block = 4 waves = 4 channel groups.
// x2 rows h0-1..h0+4 (6 rows per 4 r-rows = 1.5x amplification, was 2.0x).
// Depth-2 channel prefetch; XCD-chunked quad mapping; two-round LDS reduction.
__global__ __launch_bounds__(256, 2) void corr_r_kernel(
    const float* __restrict__ x1, const float* __restrict__ x2, float* __restrict__ rws)
{
    const int tid = threadIdx.x;
    const int g   = tid >> 6;        // wave id / channel group 0..3
    const int t   = tid & 63;        // quad-col: cols 4t..4t+3
    // XCD-chunked: adjacent quads (sharing x2 halo rows) on the same XCD's L2.
    const int bid  = blockIdx.x;                 // 0..63
    const int quad = (bid & 7) * (NQUAD / 8) + (bid >> 3);
    const int b    = blockIdx.y;
    const int h0 = 4 * quad;
    const int wq = 4 * t;

    const bool vm = (h0 > 0);            // x2 row h0-1 valid
    const bool vp = (h0 + 4 < HC);       // x2 row h0+4 valid
    const int rm = vm ? h0 - 1 : 0;
    const int rp = vp ? h0 + 4 : HC - 1;

    const float* p1b = x1 + (size_t)(b * CC + g * CGW) * PLANE;
    const float* p2b = x2 + (size_t)(b * CC + g * CGW) * PLANE;

    const int o1_0 = h0 * WC + wq,       o1_1 = (h0 + 1) * WC + wq;
    const int o1_2 = (h0 + 2) * WC + wq, o1_3 = (h0 + 3) * WC + wq;
    const int o2_0 = rm * WC + wq,       o2_5 = rp * WC + wq;
    // o2_1..o2_4 == o1_0..o1_3 (same rows)

    const float4 fz = make_float4(0.f, 0.f, 0.f, 0.f);
    float4 acc[4][9];
#pragma unroll
    for (int i = 0; i < 4; ++i)
#pragma unroll
        for (int d = 0; d < 9; ++d) acc[i][d] = fz;

    // depth-2 prefetch slots: 4 x1 quads + 6 x2 quads per channel
    float4 A[2][4], Q[2][6];

#define ISSUE(s, cc)                                                           \
    do {                                                                       \
        const float* P1 = p1b + (size_t)(cc) * PLANE;                          \
        const float* P2 = p2b + (size_t)(cc) * PLANE;                          \
        A[s][0] = ld4(P1 + o1_0);                                              \
        A[s][1] = ld4(P1 + o1_1);                                              \
        A[s][2] = ld4(P1 + o1_2);                                              \
        A[s][3] = ld4(P1 + o1_3);                                              \
        Q[s][0] = vm ? ld4(P2 + o2_0) : fz;                                    \
        Q[s][1] = ld4(P2 + o1_0);                                              \
        Q[s][2] = ld4(P2 + o1_1);                                              \
        Q[s][3] = ld4(P2 + o1_2);                                              \
        Q[s][4] = ld4(P2 + o1_3);                                              \
        Q[s][5] = vp ? ld4(P2 + o2_5) : fz;                                    \
    } while (0)

#define COMPUTE_STEP(s)                                                        \
    do {                                                                       \
        float pw[6], nx[6];                                                    \
        _Pragma("unroll")                                                      \
        for (int j = 0; j < 6; ++j) {                                          \
            pw[j] = __shfl_up(Q[s][j].w, 1);                                   \
            nx[j] = __shfl_down(Q[s][j].x, 1);                                 \
            if (t == 0)  pw[j] = 0.f;                                          \
            if (t == 63) nx[j] = 0.f;                                          \
        }                                                                      \
        _Pragma("unroll")                                                      \
        for (int i = 0; i < 4; ++i) {                                          \
            _Pragma("unroll")                                                  \
            for (int k = 0; k < 3; ++k) {                                      \
                const int j = i + k;     /* x2 row h0+i-1+k */                 \
                tap6(acc[i][3 * k], acc[i][3 * k + 1], acc[i][3 * k + 2],      \
                     A[s][i], pw[j], Q[s][j].x, Q[s][j].y, Q[s][j].z,          \
                     Q[s][j].w, nx[j]);                                        \
            }                                                                  \
        }                                                                      \
    } while (0)

    ISSUE(0, 0);
    ISSUE(1, 1);
#pragma unroll 2
    for (int c = 0; c < CGW; ++c) {
        const int s = c & 1;
        COMPUTE_STEP(s);
        if (c + 2 < CGW) ISSUE(s, c + 2);
    }
#undef ISSUE
#undef COMPUTE_STEP

    // ---- cross-wave reduction: two rounds (rows 0-1, rows 2-3) over 2 x 18.4 KB buffers ----
    __shared__ __align__(16) float buf[2][9][2][WC];   // 36,864 B

#define WBUF(i, ra, rb)                                                      \
    do {                                                                     \
        _Pragma("unroll")                                                    \
        for (int d = 0; d < 9; ++d) {                                        \
            st4(&buf[i][d][0][wq], acc[ra][d]);                              \
            st4(&buf[i][d][1][wq], acc[rb][d]);                              \
        }                                                                    \
    } while (0)
#define ABUF(i, ra, rb)                                                      \
    do {                                                                     \
        _Pragma("unroll")                                                    \
        for (int d = 0; d < 9; ++d) {                                        \
            float4 v0 = ld4(&buf[i][d][0][wq]);                              \
            float4 v1 = ld4(&buf[i][d][1][wq]);                              \
            acc[ra][d].x += v0.x; acc[ra][d].y += v0.y;                      \
            acc[ra][d].z += v0.z; acc[ra][d].w += v0.w;                      \
            acc[rb][d].x += v1.x; acc[rb][d].y += v1.y;                      \
            acc[rb][d].z += v1.z; acc[rb][d].w += v1.w;                      \
        }                                                                    \
    } while (0)

#pragma unroll
    for (int half = 0; half < 2; ++half) {
        const int ra = 2 * half, rb = 2 * half + 1;
        if (g == 1) WBUF(0, ra, rb);
        if (g == 3) WBUF(1, ra, rb);
        __syncthreads();
        if (g == 0) ABUF(0, ra, rb);
        if (g == 2) ABUF(1, ra, rb);
        __syncthreads();
        if (g == 2) WBUF(0, ra, rb);
        __syncthreads();
        if (g == 0) {
            ABUF(0, ra, rb);
#pragma unroll
            for (int d = 0; d < 9; ++d) {
                float* base = rws + (((size_t)(b * 9 + d) * HC) + h0 + ra) * WC;
                st4(base + wq, acc[ra][d]);
                st4(base + WC + wq, acc[rb][d]);
            }
        }
        __syncthreads();
    }
#undef WBUF
#undef ABUF
}

// ---------------- kernel 2: out = (1/864) * 3x3 box over r ----------------
// one wave per (b,d,y); lanes = quad-cols; left halo via shfl; lane 63 also emits cols 256,257.
__global__ __launch_bounds__(256) void corr_box_kernel(
    const float* __restrict__ rws, float* __restrict__ out)
{
    const int tid = threadIdx.x;
    const int wid = tid >> 6, t = tid & 63;
    const int job = blockIdx.x * 4 + wid;
    if (job >= K2_JOBS) return;
    const int y  = job % OH;
    const int bd = job / OH;
    const float* rp = rws + (size_t)bd * PLANE;

    float4 s4 = make_float4(0.f, 0.f, 0.f, 0.f);
    float s256 = 0.f, s257 = 0.f;
#pragma unroll
    for (int k = 0; k < 3; ++k) {
        const int rr = y - 2 + k;
        if ((unsigned)rr < (unsigned)HC) {
            float4 q = ld4(rp + rr * WC + 4 * t);
            float pz = __shfl_up(q.z, 1);
            float pw = __shfl_up(q.w, 1);
            if (t == 0) { pz = 0.f; pw = 0.f; }
            s4.x += pz + pw + q.x;
            s4.y += pw + q.x + q.y;
            s4.z += q.x + q.y + q.z;
            s4.w += q.y + q.z + q.w;
            s256 += q.z + q.w;   // out col 256: r cols 254,255
            s257 += q.w;         // out col 257: r col 255
        }
    }
    float* orow = out + ((size_t)bd * OH + y) * OW;
    const float sc = 1.0f / 864.0f;
    orow[4 * t]     = s4.x * sc;
    orow[4 * t + 1] = s4.y * sc;
    orow[4 * t + 2] = s4.z * sc;
    orow[4 * t + 3] = s4.w * sc;
    if (t == 63) { orow[256] = s256 * sc; orow[257] = s257 * sc; }
}

// ---------------- fallback (ws too small): Round-0 verified kernel ----------------
#define FBTOX 30
#define FBTOY 14
__global__ __launch_bounds__(256) void corr2d_fb(
    const float* __restrict__ x1, const float* __restrict__ x2, float* __restrict__ out)
{
    const int tx = threadIdx.x, ty = threadIdx.y;
    const int bx = blockIdx.x, by = blockIdx.y, b = blockIdx.z;
    const int x0 = bx * FBTOX, y0 = by * FBTOY;
    const int w = x0 - 2 + tx;
    const int h0 = y0 - 2 + ty, h1 = h0 + 8;
    const size_t plane = (size_t)HC * WC;
    const float* p1 = x1 + (size_t)b * CC * plane;
    const float* p2 = x2 + (size_t)b * CC * plane;
    float acc[2][9];
#pragma unroll
    for (int i = 0; i < 2; ++i)
#pragma unroll
        for (int d = 0; d < 9; ++d) acc[i][d] = 0.f;
    const bool interior = (x0 >= 3) && (x0 + 30 <= WC - 1) && (y0 >= 3) && (y0 + 14 <= HC - 1);
    if (interior) {
        const float* q1 = p1 + (size_t)(h0 * WC + w);
        const float* q2 = p2 + (size_t)(h0 * WC + w);
        for (int c = 0; c < CC; ++c) {
            const float a0 = q1[0];
            const float a1 = q1[8 * WC];
#pragma unroll
            for (int tj = -1; tj <= 1; ++tj)
#pragma unroll
                for (int ti = -1; ti <= 1; ++ti) {
                    const int d = (tj + 1) * 3 + (ti + 1);
                    acc[0][d] = fmaf(a0, q2[tj * WC + ti], acc[0][d]);
                    acc[1][d] = fmaf(a1, q2[(tj + 8) * WC + ti], acc[1][d]);
                }
            q1 += plane; q2 += plane;
        }
    } else {
        int rows[6]; bool rv[6];
        const int hh[6] = {h0 - 1, h0, h0 + 1, h1 - 1, h1, h1 + 1};
#pragma unroll
        for (int j = 0; j < 6; ++j) {
            rv[j] = ((unsigned)hh[j] < (unsigned)HC);
            int hcl = hh[j] < 0 ? 0 : (hh[j] > HC - 1 ? HC - 1 : hh[j]);
            rows[j] = hcl * WC;
        }
        int cols[3]; bool cv[3];
#pragma unroll
        for (int i = 0; i < 3; ++i) {
            int ww = w - 1 + i;
            cv[i] = ((unsigned)ww < (unsigned)WC);
            cols[i] = ww < 0 ? 0 : (ww > WC - 1 ? WC - 1 : ww);
        }
        const bool v0 = ((unsigned)h0 < (unsigned)HC) && ((unsigned)w < (unsigned)WC);
        const bool v1 = ((unsigned)h1 < (unsigned)HC) && ((unsigned)w < (unsigned)WC);
        const int wcl = w < 0 ? 0 : (w > WC - 1 ? WC - 1 : w);
        const int off1_0 = (h0 < 0 ? 0 : (h0 > HC - 1 ? HC - 1 : h0)) * WC + wcl;
        const int off1_1 = (h1 < 0 ? 0 : (h1 > HC - 1 ? HC - 1 : h1)) * WC + wcl;
        const float* q1 = p1;
        const float* q2 = p2;
        for (int c = 0; c < CC; ++c) {
            const float a0 = v0 ? q1[off1_0] : 0.f;
            const float a1 = v1 ? q1[off1_1] : 0.f;
#pragma unroll
            for (int jr = 0; jr < 3; ++jr)
#pragma unroll
                for (int i = 0; i < 3; ++i) {
                    const int d = jr * 3 + i;
                    const float u0 = (rv[jr] && cv[i])     ? q2[rows[jr] + cols[i]]     : 0.f;
                    const float u1 = (rv[jr + 3] && cv[i]) ? q2[rows[jr + 3] + cols[i]] : 0.f;
                    acc[0][d] = fmaf(a0, u0, acc[0][d]);
                    acc[1][d] = fmaf(a1, u1, acc[1][d]);
                }
            q1 += plane; q2 += plane;
        }
    }
    __shared__ float rl[9][16][32];
#pragma unroll
    for (int d = 0; d < 9; ++d) {
        rl[d][ty][tx]     = acc[0][d];
        rl[d][ty + 8][tx] = acc[1][d];
    }
    __syncthreads();
    const int tid = ty * 32 + tx;
    for (int j = tid; j < FBTOX * FBTOY; j += 256) {
        const int oy = j / FBTOX, ox = j - oy * FBTOX;
        const int y = y0 + oy, x = x0 + ox;
        if (y < OH && x < OW) {
#pragma unroll
            for (int d = 0; d < 9; ++d) {
                float s = 0.f;
#pragma unroll
                for (int a = 0; a < 3; ++a)
#pragma unroll
                    for (int b2 = 0; b2 < 3; ++b2)
                        s += rl[d][oy + a][ox + b2];
                out[(((size_t)b * 9 + d) * OH + y) * OW + x] = s * (1.0f / 864.0f);
            }
        }
    }
}

extern "C" void kernel_launch(void* const* d_in, const int* in_sizes, int n_in,
                              void* d_out, int out_size, void* d_ws, size_t ws_size,
                              hipStream_t stream) {
    const float* x1 = (const float*)d_in[0];
    const float* x2 = (const float*)d_in[1];
    float* out = (float*)d_out;
    if (ws_size >= WS_NEEDED) {
        float* rws = (float*)d_ws;
        hipLaunchKernelGGL(corr_r_kernel, dim3(NQUAD, BB), dim3(256), 0, stream, x1, x2, rws);
        hipLaunchKernelGGL(corr_box_kernel, dim3(K2_BLOCKS), dim3(256), 0, stream, rws, out);
    } else {
        hipLaunchKernelGGL(corr2d_fb,
                           dim3((OW + FBTOX - 1) / FBTOX, (OH + FBTOY - 1) / FBTOY, BB),
                           dim3(32, 8), 0, stream, x1, x2, out);
    }
}

// Round 12
// 63.656 us; speedup vs baseline: 2.7172x; 2.7172x over previous
//
#include <hip/hip_runtime.h>

#define HC 256
#define WC 256
#define CC 96
#define BB 4
#define OH 258
#define OW 258
#define PLANE 65536
#define NPAIR 128                    // 256 r-rows as 128 pairs
#define CGW 24                       // channels per wave (4 waves/block)
#define K2_JOBS (BB * 9 * OH)        // 9288 (one wave per out row)
#define K2_BLOCKS ((K2_JOBS + 3) / 4)
#define WS_NEEDED ((size_t)BB * 9 * PLANE * 4)   // 9.44 MB of r

__device__ __forceinline__ float4 ld4(const float* p){ return *reinterpret_cast<const float4*>(p); }
__device__ __forceinline__ void st4(float* p, float4 v){ *reinterpret_cast<float4*>(p) = v; }

// acc[A..C] = d0..d0+2 (ti=0,1,2); window w0..w5 = x2 cols 4t-1 .. 4t+4
__device__ __forceinline__ void tap6(float4& A, float4& B, float4& C, const float4 a,
                                     float w0, float w1, float w2, float w3, float w4, float w5)
{
    A.x = fmaf(a.x, w0, A.x); A.y = fmaf(a.y, w1, A.y); A.z = fmaf(a.z, w2, A.z); A.w = fmaf(a.w, w3, A.w);
    B.x = fmaf(a.x, w1, B.x); B.y = fmaf(a.y, w2, B.y); B.z = fmaf(a.z, w3, B.z); B.w = fmaf(a.w, w4, B.w);
    C.x = fmaf(a.x, w2, C.x); C.y = fmaf(a.y, w3, C.y); C.z = fmaf(a.z, w4, C.z); C.w = fmaf(a.w, w5, C.w);
}

// ---------------- kernel 1: r(h,w,d) = sum_c x1[c,h,w]*x2[c,h+tj-1,w+ti-1] ----------------
// wave = full 256-wide row-pair (h0,h1) x 24 channels; block = 4 waves = 4 channel groups.
// Depth-3 channel prefetch (three register slots, literal indices); XCD-chunked pair map.
__global__ __launch_bounds__(256) void corr_r_kernel(
    const float* __restrict__ x1, const float* __restrict__ x2, float* __restrict__ rws)
{
    const int tid = threadIdx.x;
    const int g   = tid >> 6;        // wave id / channel group 0..3
    const int t   = tid & 63;        // quad-col: cols 4t..4t+3
    // XCD-chunked: adjacent pairs (sharing x2 halo rows) on the same XCD's L2.
    const int bid  = blockIdx.x;                 // 0..127
    const int pair = (bid & 7) * (NPAIR / 8) + (bid >> 3);
    const int b    = blockIdx.y;
    const int h0 = 2 * pair, h1 = h0 + 1;
    const int wq = 4 * t;

    const bool vm1 = (h0 > 0);
    const bool vp2 = (h1 < HC - 1);
    const int rm1 = vm1 ? h0 - 1 : 0;
    const int rp2 = vp2 ? h1 + 1 : HC - 1;

    const float* p1b = x1 + (size_t)(b * CC + g * CGW) * PLANE;
    const float* p2b = x2 + (size_t)(b * CC + g * CGW) * PLANE;

    const int o1a = h0 * WC + wq, o1b = h1 * WC + wq;
    const int o20 = rm1 * WC + wq, o21 = h0 * WC + wq, o22 = h1 * WC + wq, o23 = rp2 * WC + wq;

    const float4 fz = make_float4(0.f, 0.f, 0.f, 0.f);
    float4 acc0[9], acc1[9];
#pragma unroll
    for (int d = 0; d < 9; ++d) { acc0[d] = fz; acc1[d] = fz; }

    // three prefetch slots (depth-3 pipeline), all indices literal
    float4 A0[3], A1[3], Q0[3], Q1[3], Q2[3], Q3[3];

#define ISSUE(s, cc)                                                           \
    do {                                                                       \
        const float* P1 = p1b + (size_t)(cc) * PLANE;                          \
        const float* P2 = p2b + (size_t)(cc) * PLANE;                          \
        A0[s] = ld4(P1 + o1a);                                                 \
        A1[s] = ld4(P1 + o1b);                                                 \
        Q0[s] = vm1 ? ld4(P2 + o20) : fz;                                      \
        Q1[s] = ld4(P2 + o21);                                                 \
        Q2[s] = ld4(P2 + o22);                                                 \
        Q3[s] = vp2 ? ld4(P2 + o23) : fz;                                      \
    } while (0)

#define COMPUTE_STEP(s)                                                                          \
    do {                                                                                         \
        float pw0 = __shfl_up(Q0[s].w, 1), nx0 = __shfl_down(Q0[s].x, 1);                        \
        float pw1 = __shfl_up(Q1[s].w, 1), nx1 = __shfl_down(Q1[s].x, 1);                        \
        float pw2 = __shfl_up(Q2[s].w, 1), nx2 = __shfl_down(Q2[s].x, 1);                        \
        float pw3 = __shfl_up(Q3[s].w, 1), nx3 = __shfl_down(Q3[s].x, 1);                        \
        if (t == 0)  { pw0 = 0; pw1 = 0; pw2 = 0; pw3 = 0; }                                     \
        if (t == 63) { nx0 = 0; nx1 = 0; nx2 = 0; nx3 = 0; }                                     \
        tap6(acc0[0], acc0[1], acc0[2], A0[s], pw0, Q0[s].x, Q0[s].y, Q0[s].z, Q0[s].w, nx0);    \
        tap6(acc0[3], acc0[4], acc0[5], A0[s], pw1, Q1[s].x, Q1[s].y, Q1[s].z, Q1[s].w, nx1);    \
        tap6(acc1[0], acc1[1], acc1[2], A1[s], pw1, Q1[s].x, Q1[s].y, Q1[s].z, Q1[s].w, nx1);    \
        tap6(acc0[6], acc0[7], acc0[8], A0[s], pw2, Q2[s].x, Q2[s].y, Q2[s].z, Q2[s].w, nx2);    \
        tap6(acc1[3], acc1[4], acc1[5], A1[s], pw2, Q2[s].x, Q2[s].y, Q2[s].z, Q2[s].w, nx2);    \
        tap6(acc1[6], acc1[7], acc1[8], A1[s], pw3, Q3[s].x, Q3[s].y, Q3[s].z, Q3[s].w, nx3);    \
    } while (0)

    ISSUE(0, 0);
    ISSUE(1, 1);
    ISSUE(2, 2);
    for (int c = 0; c < CGW; c += 3) {   // CGW % 3 == 0; all slot indices literal
        COMPUTE_STEP(0);
        if (c + 3 < CGW) ISSUE(0, c + 3);
        COMPUTE_STEP(1);
        if (c + 4 < CGW) ISSUE(1, c + 4);
        COMPUTE_STEP(2);
        if (c + 5 < CGW) ISSUE(2, c + 5);
    }
#undef ISSUE
#undef COMPUTE_STEP

    // ---- reduce the 4 waves' partials in LDS (contiguous float4 rows: conflict-free) ----
    __shared__ __align__(16) float red[9][2][WC];   // 18432 B
    for (int r = 0; r < 4; ++r) {
        if (g == r) {
#pragma unroll
            for (int d = 0; d < 9; ++d) {
                float* d0p = &red[d][0][wq];
                float* d1p = &red[d][1][wq];
                if (r == 0) { st4(d0p, acc0[d]); st4(d1p, acc1[d]); }
                else {
                    float4 v0 = ld4(d0p), v1 = ld4(d1p);
                    v0.x += acc0[d].x; v0.y += acc0[d].y; v0.z += acc0[d].z; v0.w += acc0[d].w;
                    v1.x += acc1[d].x; v1.y += acc1[d].y; v1.z += acc1[d].z; v1.w += acc1[d].w;
                    st4(d0p, v0); st4(d1p, v1);
                }
            }
        }
        __syncthreads();
    }

    // ---- write r rows (h0,h1) to workspace: rws[b][d][h][w] ----
    for (int idx = tid; idx < 9 * 2 * 64; idx += 256) {
        const int t2 = idx & 63;
        const int ds = idx >> 6;
        const int s  = ds & 1;
        const int d  = ds >> 1;
        float4 v = ld4(&red[d][s][4 * t2]);
        st4(rws + (((size_t)(b * 9 + d) * HC) + (h0 + s)) * WC + 4 * t2, v);
    }
}

// ---------------- kernel 2: out = (1/864) * 3x3 box over r ----------------
// one wave per (b,d,y); lanes = quad-cols; left halo via shfl; lane 63 also emits cols 256,257.
__global__ __launch_bounds__(256) void corr_box_kernel(
    const float* __restrict__ rws, float* __restrict__ out)
{
    const int tid = threadIdx.x;
    const int wid = tid >> 6, t = tid & 63;
    const int job = blockIdx.x * 4 + wid;
    if (job >= K2_JOBS) return;
    const int y  = job % OH;
    const int bd = job / OH;
    const float* rp = rws + (size_t)bd * PLANE;

    float4 s4 = make_float4(0.f, 0.f, 0.f, 0.f);
    float s256 = 0.f, s257 = 0.f;
#pragma unroll
    for (int k = 0; k < 3; ++k) {
        const int rr = y - 2 + k;
        if ((unsigned)rr < (unsigned)HC) {
            float4 q = ld4(rp + rr * WC + 4 * t);
            float pz = __shfl_up(q.z, 1);
            float pw = __shfl_up(q.w, 1);
            if (t == 0) { pz = 0.f; pw = 0.f; }
            s4.x += pz + pw + q.x;
            s4.y += pw + q.x + q.y;
            s4.z += q.x + q.y + q.z;
            s4.w += q.y + q.z + q.w;
            s256 += q.z + q.w;   // out col 256: r cols 254,255
            s257 += q.w;         // out col 257: r col 255
        }
    }
    float* orow = out + ((size_t)bd * OH + y) * OW;
    const float sc = 1.0f / 864.0f;
    orow[4 * t]     = s4.x * sc;
    orow[4 * t + 1] = s4.y * sc;
    orow[4 * t + 2] = s4.z * sc;
    orow[4 * t + 3] = s4.w * sc;
    if (t == 63) { orow[256] = s256 * sc; orow[257] = s257 * sc; }
}

// ---------------- fallback (ws too small): Round-0 verified kernel ----------------
#define FBTOX 30
#define FBTOY 14
__global__ __launch_bounds__(256) void corr2d_fb(
    const float* __restrict__ x1, const float* __restrict__ x2, float* __restrict__ out)
{
    const int tx = threadIdx.x, ty = threadIdx.y;
    const int bx = blockIdx.x, by = blockIdx.y, b = blockIdx.z;
    const int x0 = bx * FBTOX, y0 = by * FBTOY;
    const int w = x0 - 2 + tx;
    const int h0 = y0 - 2 + ty, h1 = h0 + 8;
    const size_t plane = (size_t)HC * WC;
    const float* p1 = x1 + (size_t)b * CC * plane;
    const float* p2 = x2 + (size_t)b * CC * plane;
    float acc[2][9];
#pragma unroll
    for (int i = 0; i < 2; ++i)
#pragma unroll
        for (int d = 0; d < 9; ++d) acc[i][d] = 0.f;
    const bool interior = (x0 >= 3) && (x0 + 30 <= WC - 1) && (y0 >= 3) && (y0 + 14 <= HC - 1);
    if (interior) {
        const float* q1 = p1 + (size_t)(h0 * WC + w);
        const float* q2 = p2 + (size_t)(h0 * WC + w);
        for (int c = 0; c < CC; ++c) {
            const float a0 = q1[0];
            const float a1 = q1[8 * WC];
#pragma unroll
            for (int tj = -1; tj <= 1; ++tj)
#pragma unroll
                for (int ti = -1; ti <= 1; ++ti) {
                    const int d = (tj + 1) * 3 + (ti + 1);
                    acc[0][d] = fmaf(a0, q2[tj * WC + ti], acc[0][d]);
                    acc[1][d] = fmaf(a1, q2[(tj + 8) * WC + ti], acc[1][d]);
                }
            q1 += plane; q2 += plane;
        }
    } else {
        int rows[6]; bool rv[6];
        const int hh[6] = {h0 - 1, h0, h0 + 1, h1 - 1, h1, h1 + 1};
#pragma unroll
        for (int j = 0; j < 6; ++j) {
            rv[j] = ((unsigned)hh[j] < (unsigned)HC);
            int hcl = hh[j] < 0 ? 0 : (hh[j] > HC - 1 ? HC - 1 : hh[j]);
            rows[j] = hcl * WC;
        }
        int cols[3]; bool cv[3];
#pragma unroll
        for (int i = 0; i < 3; ++i) {
            int ww = w - 1 + i;
            cv[i] = ((unsigned)ww < (unsigned)WC);
            cols[i] = ww < 0 ? 0 : (ww > WC - 1 ? WC - 1 : ww);
        }
        const bool v0 = ((unsigned)h0 < (unsigned)HC) && ((unsigned)w < (unsigned)WC);
        const bool v1 = ((unsigned)h1 < (unsigned)HC) && ((unsigned)w < (unsigned)WC);
        const int wcl = w < 0 ? 0 : (w > WC - 1 ? WC - 1 : w);
        const int off1_0 = (h0 < 0 ? 0 : (h0 > HC - 1 ? HC - 1 : h0)) * WC + wcl;
        const int off1_1 = (h1 < 0 ? 0 : (h1 > HC - 1 ? HC - 1 : h1)) * WC + wcl;
        const float* q1 = p1;
        const float* q2 = p2;
        for (int c = 0; c < CC; ++c) {
            const float a0 = v0 ? q1[off1_0] : 0.f;
            const float a1 = v1 ? q1[off1_1] : 0.f;
#pragma unroll
            for (int jr = 0; jr < 3; ++jr)
#pragma unroll
                for (int i = 0; i < 3; ++i) {
                    const int d = jr * 3 + i;
                    const float u0 = (rv[jr] && cv[i])     ? q2[rows[jr] + cols[i]]     : 0.f;
                    const float u1 = (rv[jr + 3] && cv[i]) ? q2[rows[jr + 3] + cols[i]] : 0.f;
                    acc[0][d] = fmaf(a0, u0, acc[0][d]);
                    acc[1][d] = fmaf(a1, u1, acc[1][d]);
                }
            q1 += plane; q2 += plane;
        }
    }
    __shared__ float rl[9][16][32];
#pragma unroll
    for (int d = 0; d < 9; ++d) {
        rl[d][ty][tx]     = acc[0][d];
        rl[d][ty + 8][tx] = acc[1][d];
    }
    __syncthreads();
    const int tid = ty * 32 + tx;
    for (int j = tid; j < FBTOX * FBTOY; j += 256) {
        const int oy = j / FBTOX, ox = j - oy * FBTOX;
        const int y = y0 + oy, x = x0 + ox;
        if (y < OH && x < OW) {
#pragma unroll
            for (int d = 0; d < 9; ++d) {
                float s = 0.f;
#pragma unroll
                for (int a = 0; a < 3; ++a)
#pragma unroll
                    for (int b2 = 0; b2 < 3; ++b2)
                        s += rl[d][oy + a][ox + b2];
                out[(((size_t)b * 9 + d) * OH + y) * OW + x] = s * (1.0f / 864.0f);
            }
        }
    }
}

extern "C" void kernel_launch(void* const* d_in, const int* in_sizes, int n_in,
                              void* d_out, int out_size, void* d_ws, size_t ws_size,
                              hipStream_t stream) {
    const float* x1 = (const float*)d_in[0];
    const float* x2 = (const float*)d_in[1];
    float* out = (float*)d_out;
    if (ws_size >= WS_NEEDED) {
        float* rws = (float*)d_ws;
        hipLaunchKernelGGL(corr_r_kernel, dim3(NPAIR, BB), dim3(256), 0, stream, x1, x2, rws);
        hipLaunchKernelGGL(corr_box_kernel, dim3(K2_BLOCKS), dim3(256), 0, stream, rws, out);
    } else {
        hipLaunchKernelGGL(corr2d_fb,
                           dim3((OW + FBTOX - 1) / FBTOX, (OH + FBTOY - 1) / FBTOY, BB),
                           dim3(32, 8), 0, stream, x1, x2, out);
    }
}

// Round 13
// 42.537 us; speedup vs baseline: 4.0662x; 1.4965x over previous
//
#include <hip/hip_runtime.h>

#define HC 256
#define WC 256
#define CC 96
#define BB 4
#define OH 258
#define OW 258
#define PLANE 65536
#define NPAIR 128                    // 256 r-rows as 128 pairs
#define CGW 24                       // channels per wave (4 waves/block)
#define NT_Y 65                      // ceil(258/4) 4-row tiles per (b,d)
#define K2_JOBS (BB * 9 * NT_Y)      // 2340
#define K2_BLOCKS ((K2_JOBS + 3) / 4)
#define WS_NEEDED ((size_t)BB * 9 * PLANE * 4)   // 9.44 MB of r

__device__ __forceinline__ float4 ld4(const float* p){ return *reinterpret_cast<const float4*>(p); }
__device__ __forceinline__ void st4(float* p, float4 v){ *reinterpret_cast<float4*>(p) = v; }

// acc[A..C] = d0..d0+2 (ti=0,1,2); window w0..w5 = x2 cols 4t-1 .. 4t+4
__device__ __forceinline__ void tap6(float4& A, float4& B, float4& C, const float4 a,
                                     float w0, float w1, float w2, float w3, float w4, float w5)
{
    A.x = fmaf(a.x, w0, A.x); A.y = fmaf(a.y, w1, A.y); A.z = fmaf(a.z, w2, A.z); A.w = fmaf(a.w, w3, A.w);
    B.x = fmaf(a.x, w1, B.x); B.y = fmaf(a.y, w2, B.y); B.z = fmaf(a.z, w3, B.z); B.w = fmaf(a.w, w4, B.w);
    C.x = fmaf(a.x, w2, C.x); C.y = fmaf(a.y, w3, C.y); C.z = fmaf(a.z, w4, C.z); C.w = fmaf(a.w, w5, C.w);
}

// ---------------- kernel 1 (byte-exact R9, proven 43.1 us): r = sum_c x1 * shifted x2 ----------------
// wave = full 256-wide row-pair (h0,h1) x 24 channels; block = 4 waves = 4 channel groups.
// Depth-2 channel prefetch (two register slots); XCD-chunked pair mapping for halo L2 reuse.
__global__ __launch_bounds__(256) void corr_r_kernel(
    const float* __restrict__ x1, const float* __restrict__ x2, float* __restrict__ rws)
{
    const int tid = threadIdx.x;
    const int g   = tid >> 6;        // wave id / channel group 0..3
    const int t   = tid & 63;        // quad-col: cols 4t..4t+3
    // XCD-chunked: adjacent pairs (sharing x2 halo rows) on the same XCD's L2.
    const int bid  = blockIdx.x;                 // 0..127
    const int pair = (bid & 7) * (NPAIR / 8) + (bid >> 3);
    const int b    = blockIdx.y;
    const int h0 = 2 * pair, h1 = h0 + 1;
    const int wq = 4 * t;

    const bool vm1 = (h0 > 0);
    const bool vp2 = (h1 < HC - 1);
    const int rm1 = vm1 ? h0 - 1 : 0;
    const int rp2 = vp2 ? h1 + 1 : HC - 1;

    const float* p1b = x1 + (size_t)(b * CC + g * CGW) * PLANE;
    const float* p2b = x2 + (size_t)(b * CC + g * CGW) * PLANE;

    const int o1a = h0 * WC + wq, o1b = h1 * WC + wq;
    const int o20 = rm1 * WC + wq, o21 = h0 * WC + wq, o22 = h1 * WC + wq, o23 = rp2 * WC + wq;

    const float4 fz = make_float4(0.f, 0.f, 0.f, 0.f);
    float4 acc0[9], acc1[9];
#pragma unroll
    for (int d = 0; d < 9; ++d) { acc0[d] = fz; acc1[d] = fz; }

    // two prefetch slots (depth-2 pipeline)
    float4 A0[2], A1[2], Q0[2], Q1[2], Q2[2], Q3[2];

#define ISSUE(s, cc)                                                           \
    do {                                                                       \
        const float* P1 = p1b + (size_t)(cc) * PLANE;                          \
        const float* P2 = p2b + (size_t)(cc) * PLANE;                          \
        A0[s] = ld4(P1 + o1a);                                                 \
        A1[s] = ld4(P1 + o1b);                                                 \
        Q0[s] = vm1 ? ld4(P2 + o20) : fz;                                      \
        Q1[s] = ld4(P2 + o21);                                                 \
        Q2[s] = ld4(P2 + o22);                                                 \
        Q3[s] = vp2 ? ld4(P2 + o23) : fz;                                      \
    } while (0)

#define COMPUTE_STEP(s)                                                                          \
    do {                                                                                         \
        float pw0 = __shfl_up(Q0[s].w, 1), nx0 = __shfl_down(Q0[s].x, 1);                        \
        float pw1 = __shfl_up(Q1[s].w, 1), nx1 = __shfl_down(Q1[s].x, 1);                        \
        float pw2 = __shfl_up(Q2[s].w, 1), nx2 = __shfl_down(Q2[s].x, 1);                        \
        float pw3 = __shfl_up(Q3[s].w, 1), nx3 = __shfl_down(Q3[s].x, 1);                        \
        if (t == 0)  { pw0 = 0; pw1 = 0; pw2 = 0; pw3 = 0; }                                     \
        if (t == 63) { nx0 = 0; nx1 = 0; nx2 = 0; nx3 = 0; }                                     \
        tap6(acc0[0], acc0[1], acc0[2], A0[s], pw0, Q0[s].x, Q0[s].y, Q0[s].z, Q0[s].w, nx0);    \
        tap6(acc0[3], acc0[4], acc0[5], A0[s], pw1, Q1[s].x, Q1[s].y, Q1[s].z, Q1[s].w, nx1);    \
        tap6(acc1[0], acc1[1], acc1[2], A1[s], pw1, Q1[s].x, Q1[s].y, Q1[s].z, Q1[s].w, nx1);    \
        tap6(acc0[6], acc0[7], acc0[8], A0[s], pw2, Q2[s].x, Q2[s].y, Q2[s].z, Q2[s].w, nx2);    \
        tap6(acc1[3], acc1[4], acc1[5], A1[s], pw2, Q2[s].x, Q2[s].y, Q2[s].z, Q2[s].w, nx2);    \
        tap6(acc1[6], acc1[7], acc1[8], A1[s], pw3, Q3[s].x, Q3[s].y, Q3[s].z, Q3[s].w, nx3);    \
    } while (0)

    ISSUE(0, 0);
    ISSUE(1, 1);
#pragma unroll 2
    for (int c = 0; c < CGW; ++c) {
        const int s = c & 1;
        COMPUTE_STEP(s);
        if (c + 2 < CGW) ISSUE(s, c + 2);
    }
#undef ISSUE
#undef COMPUTE_STEP

    // ---- reduce the 4 waves' partials in LDS (contiguous float4 rows: conflict-free) ----
    __shared__ __align__(16) float red[9][2][WC];   // 18432 B
    for (int r = 0; r < 4; ++r) {
        if (g == r) {
#pragma unroll
            for (int d = 0; d < 9; ++d) {
                float* d0p = &red[d][0][wq];
                float* d1p = &red[d][1][wq];
                if (r == 0) { st4(d0p, acc0[d]); st4(d1p, acc1[d]); }
                else {
                    float4 v0 = ld4(d0p), v1 = ld4(d1p);
                    v0.x += acc0[d].x; v0.y += acc0[d].y; v0.z += acc0[d].z; v0.w += acc0[d].w;
                    v1.x += acc1[d].x; v1.y += acc1[d].y; v1.z += acc1[d].z; v1.w += acc1[d].w;
                    st4(d0p, v0); st4(d1p, v1);
                }
            }
        }
        __syncthreads();
    }

    // ---- write r rows (h0,h1) to workspace: rws[b][d][h][w] ----
    for (int idx = tid; idx < 9 * 2 * 64; idx += 256) {
        const int t2 = idx & 63;
        const int ds = idx >> 6;
        const int s  = ds & 1;
        const int d  = ds >> 1;
        float4 v = ld4(&red[d][s][4 * t2]);
        st4(rws + (((size_t)(b * 9 + d) * HC) + (h0 + s)) * WC + 4 * t2, v);
    }
}

// ---------------- kernel 2 v2: 4 out-rows per wave (reads 6 r rows, was 12) ----------------
// out[y][x] = (1/864) * sum_{rows y-2..y, cols x-2..x} r; lanes = quad-cols,
// left halo via shfl; lane 63 also emits cols 256,257.
__global__ __launch_bounds__(256) void corr_box_kernel(
    const float* __restrict__ rws, float* __restrict__ out)
{
    const int tid = threadIdx.x;
    const int wid = tid >> 6, t = tid & 63;
    const int job = blockIdx.x * 4 + wid;
    if (job >= K2_JOBS) return;
    const int yt = job % NT_Y;
    const int bd = job / NT_Y;
    const int y0 = 4 * yt;
    const float* rp = rws + (size_t)bd * PLANE;

    float4 a4[4];
    float a256[4], a257[4];
#pragma unroll
    for (int i = 0; i < 4; ++i) {
        a4[i] = make_float4(0.f, 0.f, 0.f, 0.f);
        a256[i] = 0.f; a257[i] = 0.f;
    }

#pragma unroll
    for (int k = 0; k < 6; ++k) {
        const int rr = y0 - 2 + k;          // r row
        if ((unsigned)rr < (unsigned)HC) {
            float4 q = ld4(rp + rr * WC + 4 * t);
            float pz = __shfl_up(q.z, 1);
            float pw = __shfl_up(q.w, 1);
            if (t == 0) { pz = 0.f; pw = 0.f; }
            const float hx = pz + pw + q.x;
            const float hy = pw + q.x + q.y;
            const float hz = q.x + q.y + q.z;
            const float hw = q.y + q.z + q.w;
            const float h256 = q.z + q.w;   // out col 256: r cols 254,255
            const float h257 = q.w;         // out col 257: r col 255
            // row k contributes to out rows i = k-2..k (clipped to 0..3)
#pragma unroll
            for (int i = 0; i < 4; ++i) {
                if (k >= i && k <= i + 2) {
                    a4[i].x += hx; a4[i].y += hy; a4[i].z += hz; a4[i].w += hw;
                    a256[i] += h256; a257[i] += h257;
                }
            }
        }
    }

    const float sc = 1.0f / 864.0f;
#pragma unroll
    for (int i = 0; i < 4; ++i) {
        const int y = y0 + i;
        if (y < OH) {
            float* orow = out + ((size_t)bd * OH + y) * OW;
            orow[4 * t]     = a4[i].x * sc;
            orow[4 * t + 1] = a4[i].y * sc;
            orow[4 * t + 2] = a4[i].z * sc;
            orow[4 * t + 3] = a4[i].w * sc;
            if (t == 63) { orow[256] = a256[i] * sc; orow[257] = a257[i] * sc; }
        }
    }
}

// ---------------- fallback (ws too small): Round-0 verified kernel ----------------
#define FBTOX 30
#define FBTOY 14
__global__ __launch_bounds__(256) void corr2d_fb(
    const float* __restrict__ x1, const float* __restrict__ x2, float* __restrict__ out)
{
    const int tx = threadIdx.x, ty = threadIdx.y;
    const int bx = blockIdx.x, by = blockIdx.y, b = blockIdx.z;
    const int x0 = bx * FBTOX, y0 = by * FBTOY;
    const int w = x0 - 2 + tx;
    const int h0 = y0 - 2 + ty, h1 = h0 + 8;
    const size_t plane = (size_t)HC * WC;
    const float* p1 = x1 + (size_t)b * CC * plane;
    const float* p2 = x2 + (size_t)b * CC * plane;
    float acc[2][9];
#pragma unroll
    for (int i = 0; i < 2; ++i)
#pragma unroll
        for (int d = 0; d < 9; ++d) acc[i][d] = 0.f;
    const bool interior = (x0 >= 3) && (x0 + 30 <= WC - 1) && (y0 >= 3) && (y0 + 14 <= HC - 1);
    if (interior) {
        const float* q1 = p1 + (size_t)(h0 * WC + w);
        const float* q2 = p2 + (size_t)(h0 * WC + w);
        for (int c = 0; c < CC; ++c) {
            const float a0 = q1[0];
            const float a1 = q1[8 * WC];
#pragma unroll
            for (int tj = -1; tj <= 1; ++tj)
#pragma unroll
                for (int ti = -1; ti <= 1; ++ti) {
                    const int d = (tj + 1) * 3 + (ti + 1);
                    acc[0][d] = fmaf(a0, q2[tj * WC + ti], acc[0][d]);
                    acc[1][d] = fmaf(a1, q2[(tj + 8) * WC + ti], acc[1][d]);
                }
            q1 += plane; q2 += plane;
        }
    } else {
        int rows[6]; bool rv[6];
        const int hh[6] = {h0 - 1, h0, h0 + 1, h1 - 1, h1, h1 + 1};
#pragma unroll
        for (int j = 0; j < 6; ++j) {
            rv[j] = ((unsigned)hh[j] < (unsigned)HC);
            int hcl = hh[j] < 0 ? 0 : (hh[j] > HC - 1 ? HC - 1 : hh[j]);
            rows[j] = hcl * WC;
        }
        int cols[3]; bool cv[3];
#pragma unroll
        for (int i = 0; i < 3; ++i) {
            int ww = w - 1 + i;
            cv[i] = ((unsigned)ww < (unsigned)WC);
            cols[i] = ww < 0 ? 0 : (ww > WC - 1 ? WC - 1 : ww);
        }
        const bool v0 = ((unsigned)h0 < (unsigned)HC) && ((unsigned)w < (unsigned)WC);
        const bool v1 = ((unsigned)h1 < (unsigned)HC) && ((unsigned)w < (unsigned)WC);
        const int wcl = w < 0 ? 0 : (w > WC - 1 ? WC - 1 : w);
        const int off1_0 = (h0 < 0 ? 0 : (h0 > HC - 1 ? HC - 1 : h0)) * WC + wcl;
        const int off1_1 = (h1 < 0 ? 0 : (h1 > HC - 1 ? HC - 1 : h1)) * WC + wcl;
        const float* q1 = p1;
        const float* q2 = p2;
        for (int c = 0; c < CC; ++c) {
            const float a0 = v0 ? q1[off1_0] : 0.f;
            const float a1 = v1 ? q1[off1_1] : 0.f;
#pragma unroll
            for (int jr = 0; jr < 3; ++jr)
#pragma unroll
                for (int i = 0; i < 3; ++i) {
                    const int d = jr * 3 + i;
                    const float u0 = (rv[jr] && cv[i])     ? q2[rows[jr] + cols[i]]     : 0.f;
                    const float u1 = (rv[jr + 3] && cv[i]) ? q2[rows[jr + 3] + cols[i]] : 0.f;
                    acc[0][d] = fmaf(a0, u0, acc[0][d]);
                    acc[1][d] = fmaf(a1, u1, acc[1][d]);
                }
            q1 += plane; q2 += plane;
        }
    }
    __shared__ float rl[9][16][32];
#pragma unroll
    for (int d = 0; d < 9; ++d) {
        rl[d][ty][tx]     = acc[0][d];
        rl[d][ty + 8][tx] = acc[1][d];
    }
    __syncthreads();
    const int tid = ty * 32 + tx;
    for (int j = tid; j < FBTOX * FBTOY; j += 256) {
        const int oy = j / FBTOX, ox = j - oy * FBTOX;
        const int y = y0 + oy, x = x0 + ox;
        if (y < OH && x < OW) {
#pragma unroll
            for (int d = 0; d < 9; ++d) {
                float s = 0.f;
#pragma unroll
                for (int a = 0; a < 3; ++a)
#pragma unroll
                    for (int b2 = 0; b2 < 3; ++b2)
                        s += rl[d][oy + a][ox + b2];
                out[(((size_t)b * 9 + d) * OH + y) * OW + x] = s * (1.0f / 864.0f);
            }
        }
    }
}

extern "C" void kernel_launch(void* const* d_in, const int* in_sizes, int n_in,
                              void* d_out, int out_size, void* d_ws, size_t ws_size,
                              hipStream_t stream) {
    const float* x1 = (const float*)d_in[0];
    const float* x2 = (const float*)d_in[1];
    float* out = (float*)d_out;
    if (ws_size >= WS_NEEDED) {
        float* rws = (float*)d_ws;
        hipLaunchKernelGGL(corr_r_kernel, dim3(NPAIR, BB), dim3(256), 0, stream, x1, x2, rws);
        hipLaunchKernelGGL(corr_box_kernel, dim3(K2_BLOCKS), dim3(256), 0, stream, rws, out);
    } else {
        hipLaunchKernelGGL(corr2d_fb,
                           dim3((OW + FBTOX - 1) / FBTOX, (OH + FBTOY - 1) / FBTOY, BB),
                           dim3(32, 8), 0, stream, x1, x2, out);
    }
}